// Round 4
// baseline (239.602 us; speedup 1.0000x reference)
//
#include <hip/hip_runtime.h>
#include <stdint.h>

#define M_DIM 4096
#define N_DIM 4096
#define K_DIM 4096
#define BM 128
#define BN 128
#define BKB 128   // K-bytes (= i8 elems) per tile
#define NT 4      // gate tiles
#define TCOLS (N_DIM / NT)   // 1024 output cols per gate tile

// cvt geometry: 1 f32x4 quad per thread (max TLP — R1/R2/R3 showed more
// threads beats more ILP for this latency-bound streaming kernel)
#define NXB 16384            // x blocks:  16384*256 = 4,194,304 quads = 64 MB
#define NWB 16384            // w blocks
#define NZROWS 4096          // zero-fill rows, folded into first 4096 x-blocks

typedef __attribute__((ext_vector_type(4)))  int     int4v;
typedef __attribute__((ext_vector_type(4)))  float   f32x4;

#define XSCALE (127.0f / 4.25f)
#define XDEQ   (4.25f / 127.0f)

// ---------------- fp32 -> i8 quantizers ----------------
__device__ __forceinline__ uint32_t q8b(float v) {
    float c = fminf(fmaxf(v * XSCALE, -127.0f), 127.0f);
    return (uint32_t)(uint8_t)(int8_t)(int)__builtin_rintf(c);
}
__device__ __forceinline__ uint32_t s8b(float v) {         // exact ternary sign
    return (uint32_t)(uint8_t)(int8_t)((v > 0.0f) - (v < 0.0f));
}
__device__ __forceinline__ uint32_t pack_q8(f32x4 a) {
    return q8b(a[0]) | (q8b(a[1]) << 8) | (q8b(a[2]) << 16) | (q8b(a[3]) << 24);
}
__device__ __forceinline__ uint32_t pack_s8(f32x4 a) {
    return s8b(a[0]) | (s8b(a[1]) << 8) | (s8b(a[2]) << 16) | (s8b(a[3]) << 24);
}

// Roles by block id:
//   [0, NXB)            : quantize x, 1 quad/thread (wave: 1KB packed load,
//                         256B packed store). Blocks < NZROWS also zero-fill
//                         one output row's gated-off tiles.
//   [NXB, NXB+NWB)      : sign-pack w, 1 quad/thread.
//   [NXB+NWB, +NT)      : per-tile row compaction (LDS counter).
__global__ __launch_bounds__(256) void cvt_i8_kernel(const float* __restrict__ x,
                                                     const float* __restrict__ w,
                                                     int8_t* __restrict__ xq,
                                                     int8_t* __restrict__ wq,
                                                     const int* __restrict__ gate,
                                                     float* __restrict__ out,
                                                     int* __restrict__ rowlist,
                                                     int* __restrict__ counts) {
    const int tid = threadIdx.x;
    const int bid = blockIdx.x;

    if (bid >= NXB + NWB) {          // ---- compaction: one block per gate tile ----
        const int t = bid - (NXB + NWB);
        __shared__ int lcnt;
        if (tid == 0) lcnt = 0;
        __syncthreads();
        const int lane = tid & 63;
        for (int i = 0; i < 16; ++i) {
            int row  = i * 256 + tid;
            int pred = (gate[row * NT + t] != 0);
            unsigned long long m = __ballot(pred);
            if (m != 0) {
                int leader = __ffsll((long long)m) - 1;
                int base = 0;
                if (lane == leader) base = atomicAdd(&lcnt, (int)__popcll(m));
                base = __shfl(base, leader);
                if (pred) {
                    int prefix = (int)__popcll(m & ((1ull << lane) - 1ull));
                    rowlist[t * M_DIM + base + prefix] = row;
                }
            }
        }
        __syncthreads();
        if (tid == 0) counts[t] = lcnt;
        return;
    }

    if (bid < NXB) {                 // ---- x: quantize ----
        if (bid < NZROWS) {          // zero-fill one output row (block-uniform)
            const int row = bid;
            f32x4 z = {0.f, 0.f, 0.f, 0.f};
#pragma unroll
            for (int t = 0; t < NT; ++t) {
                if (gate[row * NT + t] == 0) {
                    *(f32x4*)(out + (size_t)row * N_DIM + t * TCOLS + tid * 4) = z;
                }
            }
        }
        const size_t q = (size_t)bid * 256 + tid;
        f32x4 a = ((const f32x4*)x)[q];
        ((uint32_t*)xq)[q] = pack_q8(a);
    } else {                         // ---- w: sign ----
        const size_t q = (size_t)(bid - NXB) * 256 + tid;
        f32x4 a = ((const f32x4*)w)[q];
        ((uint32_t*)wq)[q] = pack_s8(a);
    }
}

// ---------------- async global->LDS, 16B per lane ----------------
__device__ __forceinline__ void gload_lds16(const int8_t* g, int8_t* l) {
    __builtin_amdgcn_global_load_lds(
        (__attribute__((address_space(1))) void*)(g),
        (__attribute__((address_space(3))) void*)(l),
        16, 0, 0);
}

// ---------------- i8 GEMM over the COMPACTED row domain ----------------
// T1: bijective XCD-chunked swizzle (nwg = 1024, 8 XCDs, 128 blocks each).
// XCD k owns bx in [4k, 4k+4) x all by: its 4 B-panels (4 x 512 KB = 2 MB)
// stay L2-resident and are reused by up to 32 blocks each.
__global__ __launch_bounds__(256, 2) void trix_gemm(
    const int8_t* __restrict__ A,        // xq i8 [4096][4096]
    const int8_t* __restrict__ B,        // wq i8 [4096][4096] (O-major, K contig)
    const int* __restrict__ gate,        // [4096][4]
    const float* __restrict__ scales,    // [4096]
    const int* __restrict__ rowlist,     // [4][4096] compacted row ids
    const int* __restrict__ counts,      // [4]
    float* __restrict__ out)             // [4096][4096] fp32
{
    // dispatch-order id -> (bx, by) via chunked swizzle
    const int fid = blockIdx.y * 32 + blockIdx.x;     // 0..1023, HW round-robins %8
    const int lid = (fid & 7) * 128 + (fid >> 3);     // bijective (1024 % 8 == 0)
    const int bx  = lid >> 5;                         // 0..31  (4 per XCD)
    const int by  = lid & 31;                         // 0..31

    const int tile = bx >> 3;                 // 8 n-blocks per gate tile
    const int cnt  = counts[tile];
    const int m0   = by * BM;                 // position in compacted domain
    if (m0 >= cnt) return;

    __shared__ __align__(16) int8_t As[BM * BKB];   // 16 KB
    __shared__ __align__(16) int8_t Bs[BN * BKB];   // 16 KB

    const int tid  = threadIdx.x;
    const int lane = tid & 63;
    const int wave = tid >> 6;       // 0..3
    const int wm   = wave >> 1;      // 0..1
    const int wn   = wave & 1;       // 0..1
    const int quad = lane >> 4;      // 0..3
    const int ln16 = lane & 15;

    const int n0 = bx * BN;
    const int* rl = rowlist + tile * M_DIM;

    // ---- staging: 4 issues each for A and B per K-tile (1 KB per issue) ----
    const int srow   = lane >> 3;              // 0..7
    const int gchunk = (lane & 7) ^ srow;      // XOR swizzle in GLOBAL address
    const int8_t* a_src[4];
    const int8_t* b_src[4];
    int8_t* a_dst[4];
    int8_t* b_dst[4];
#pragma unroll
    for (int j = 0; j < 4; ++j) {
        int cidx = j * 4 + wave;
        int ra = m0 + cidx * 8 + srow;
        if (ra >= cnt) ra = cnt - 1;           // clamp surplus rows
        int grow = rl[ra];
        a_src[j] = A + (size_t)grow * K_DIM + gchunk * 16;
        b_src[j] = B + (size_t)(n0 + cidx * 8 + srow) * K_DIM + gchunk * 16;
        a_dst[j] = As + cidx * 1024;   // 8 rows x 128 B; HW adds lane*16B
        b_dst[j] = Bs + cidx * 1024;
    }

    // ---- fragment read addresses: lane reads 16 i8 at row, k = quad*16 + kk*64 ----
    const int8_t* a_rd[4][2];
    const int8_t* b_rd[4][2];
#pragma unroll
    for (int i = 0; i < 4; ++i) {
        int arow = wm * 64 + i * 16 + ln16;
        int brow = wn * 64 + i * 16 + ln16;
#pragma unroll
        for (int kk = 0; kk < 2; ++kk) {
            int ch = quad + 4 * kk;
            a_rd[i][kk] = As + arow * 128 + ((ch ^ (arow & 7)) * 16);
            b_rd[i][kk] = Bs + brow * 128 + ((ch ^ (brow & 7)) * 16);
        }
    }

    int4v acc[4][4];
#pragma unroll
    for (int i = 0; i < 4; ++i)
#pragma unroll
        for (int j = 0; j < 4; ++j)
            acc[i][j] = (int4v){0, 0, 0, 0};

    for (int kt = 0; kt < K_DIM; kt += BKB) {   // 32 tiles
#pragma unroll
        for (int j = 0; j < 4; ++j) {
            gload_lds16(a_src[j], a_dst[j]);
            gload_lds16(b_src[j], b_dst[j]);
        }
#pragma unroll
        for (int j = 0; j < 4; ++j) { a_src[j] += BKB; b_src[j] += BKB; }
        __syncthreads();

#pragma unroll
        for (int kk = 0; kk < 2; ++kk) {
            int4v af[4], bf[4];
#pragma unroll
            for (int i = 0; i < 4; ++i) af[i] = *(const int4v*)a_rd[i][kk];
#pragma unroll
            for (int i = 0; i < 4; ++i) bf[i] = *(const int4v*)b_rd[i][kk];
#pragma unroll
            for (int i = 0; i < 4; ++i)
#pragma unroll
                for (int j = 0; j < 4; ++j)
                    acc[i][j] = __builtin_amdgcn_mfma_i32_16x16x64_i8(
                        af[i], bf[j], acc[i][j], 0, 0, 0);
        }
        __syncthreads();
    }

    // ---- epilogue: out[grow] = acc_i32 * dq * scales[n] * gate[grow][tile] ----
    float sc[4];
#pragma unroll
    for (int j = 0; j < 4; ++j) sc[j] = scales[n0 + wn * 64 + j * 16 + ln16] * XDEQ;

#pragma unroll
    for (int i = 0; i < 4; ++i) {
        int lbase = wm * 64 + i * 16 + quad * 4;
#pragma unroll
        for (int r = 0; r < 4; ++r) {
            int lr = lbase + r;
            if (m0 + lr < cnt) {
                int grow = rl[m0 + lr];
                float g = (float)gate[grow * NT + tile];   // generality: gate may be >1
                float* orow = out + (size_t)grow * N_DIM + n0 + wn * 64 + ln16;
#pragma unroll
                for (int j = 0; j < 4; ++j)
                    orow[j * 16] = (float)acc[i][j][r] * sc[j] * g;
            }
        }
    }
}

extern "C" void kernel_launch(void* const* d_in, const int* in_sizes, int n_in,
                              void* d_out, int out_size, void* d_ws, size_t ws_size,
                              hipStream_t stream) {
    const float* x      = (const float*)d_in[0];   // [4096][4096]
    const int*   gate   = (const int*)d_in[1];     // [4096][4]
    const float* weight = (const float*)d_in[2];   // [4096][4096]
    const float* scales = (const float*)d_in[3];   // [4096]
    float* out = (float*)d_out;

    int8_t* xq = (int8_t*)d_ws;                           // 16 MB i8 x
    int8_t* wq = xq + (size_t)M_DIM * K_DIM;              // 16 MB i8 W
    int* rowlist = (int*)(wq + (size_t)N_DIM * K_DIM);    // 64 KB: 4 x 4096 row ids
    int* counts  = rowlist + NT * M_DIM;                  // 16 B

    // one dispatch: convert + zero-fill + compact (tail blocks)
    cvt_i8_kernel<<<NXB + NWB + NT, 256, 0, stream>>>(x, weight, xq, wq,
                                                      gate, out, rowlist, counts);

    dim3 grid(N_DIM / BN, M_DIM / BM);                    // 1024 blocks, ~half active
    trix_gemm<<<grid, 256, 0, stream>>>(xq, wq, gate, scales, rowlist, counts, out);
}

// Round 5
// 231.007 us; speedup vs baseline: 1.0372x; 1.0372x over previous
//
#include <hip/hip_runtime.h>
#include <stdint.h>

#define M_DIM 4096
#define N_DIM 4096
#define K_DIM 4096
#define BM 128
#define BN 128
#define BKB 128   // K-bytes (= i8 elems) per tile
#define NT 4      // gate tiles
#define TCOLS (N_DIM / NT)   // 1024 output cols per gate tile
#define NCVB 16384           // conversion blocks (R1 geometry: 8 elems/thread)

typedef __attribute__((ext_vector_type(4)))  int     int4v;
typedef __attribute__((ext_vector_type(4)))  float   f32x4;
typedef __attribute__((ext_vector_type(8)))  uint8_t u8x8;

#define XSCALE (127.0f / 4.25f)
#define XDEQ   (4.25f / 127.0f)

// ---------------- fp32 -> i8 quantizers ----------------
__device__ __forceinline__ uint8_t q8(float v) {
    float c = fminf(fmaxf(v * XSCALE, -127.0f), 127.0f);
    return (uint8_t)(int8_t)(int)__builtin_rintf(c);
}
__device__ __forceinline__ uint8_t s8(float v) {           // exact ternary sign
    return (uint8_t)(int8_t)((v > 0.0f) - (v < 0.0f));
}

// Roles by block id:
//   [0, NCVB)        : convert (R1 geometry — measured best at 61 us):
//                      8 elems/thread, 32B NT load + 8B NT store per lane.
//                      All streams single-touch -> non-temporal (no L2/L3
//                      pollution). NO zero-fill here anymore (moved to gemm
//                      dead blocks).
//   [NCVB, NCVB+NT)  : per-tile row compaction; builds BOTH the active
//                      rowlist and the complement zrowlist.
__global__ __launch_bounds__(256) void cvt_i8_kernel(const float* __restrict__ x,
                                                     const float* __restrict__ w,
                                                     int8_t* __restrict__ xq,
                                                     int8_t* __restrict__ wq,
                                                     const int* __restrict__ gate,
                                                     int* __restrict__ rowlist,
                                                     int* __restrict__ zrowlist,
                                                     int* __restrict__ counts,
                                                     int n8each) {
    const int tid = threadIdx.x;
    const int bid = blockIdx.x;

    if (bid >= NCVB) {               // ---- compaction: one block per gate tile ----
        const int t = bid - NCVB;
        __shared__ int lcnt, zlcnt;
        if (tid == 0) { lcnt = 0; zlcnt = 0; }
        __syncthreads();
        const int lane = tid & 63;
        for (int i = 0; i < 16; ++i) {
            int row  = i * 256 + tid;
            int pred = (gate[row * NT + t] != 0);
            unsigned long long m  = __ballot(pred);
            unsigned long long mz = ~m;          // full waves: complement is exact
            if (m != 0) {
                int leader = __ffsll((long long)m) - 1;
                int base = 0;
                if (lane == leader) base = atomicAdd(&lcnt, (int)__popcll(m));
                base = __shfl(base, leader);
                if (pred) {
                    int prefix = (int)__popcll(m & ((1ull << lane) - 1ull));
                    rowlist[t * M_DIM + base + prefix] = row;
                }
            }
            if (mz != 0) {
                int leader = __ffsll((long long)mz) - 1;
                int base = 0;
                if (lane == leader) base = atomicAdd(&zlcnt, (int)__popcll(mz));
                base = __shfl(base, leader);
                if (!pred) {
                    int prefix = (int)__popcll(mz & ((1ull << lane) - 1ull));
                    zrowlist[t * M_DIM + base + prefix] = row;
                }
            }
        }
        __syncthreads();
        if (tid == 0) counts[t] = lcnt;
        return;
    }

    // ---- conversion: 8 elems/thread, non-temporal ----
    int idx = bid * 256 + tid;
    u8x8 o;
    if (idx < n8each) {
        const f32x4* s = (const f32x4*)x;
        f32x4 a = __builtin_nontemporal_load(s + (size_t)idx * 2);
        f32x4 b = __builtin_nontemporal_load(s + (size_t)idx * 2 + 1);
        o[0] = q8(a[0]); o[1] = q8(a[1]); o[2] = q8(a[2]); o[3] = q8(a[3]);
        o[4] = q8(b[0]); o[5] = q8(b[1]); o[6] = q8(b[2]); o[7] = q8(b[3]);
        __builtin_nontemporal_store(o, (u8x8*)(xq + (size_t)idx * 8));
    } else {
        int i = idx - n8each;
        const f32x4* s = (const f32x4*)w;
        f32x4 a = __builtin_nontemporal_load(s + (size_t)i * 2);
        f32x4 b = __builtin_nontemporal_load(s + (size_t)i * 2 + 1);
        o[0] = s8(a[0]); o[1] = s8(a[1]); o[2] = s8(a[2]); o[3] = s8(a[3]);
        o[4] = s8(b[0]); o[5] = s8(b[1]); o[6] = s8(b[2]); o[7] = s8(b[3]);
        __builtin_nontemporal_store(o, (u8x8*)(wq + (size_t)i * 8));
    }
}

// ---------------- async global->LDS, 16B per lane ----------------
__device__ __forceinline__ void gload_lds16(const int8_t* g, int8_t* l) {
    __builtin_amdgcn_global_load_lds(
        (__attribute__((address_space(1))) void*)(g),
        (__attribute__((address_space(3))) void*)(l),
        16, 0, 0);
}

// ---------------- i8 GEMM over the COMPACTED row domain ----------------
// Default block mapping (bx%8 is already XCD-panel-local; R4's remap regressed).
// Dead blocks (m0 >= cnt) zero-fill the gated-off rows instead of idling.
__global__ __launch_bounds__(256, 2) void trix_gemm(
    const int8_t* __restrict__ A,        // xq i8 [4096][4096]
    const int8_t* __restrict__ B,        // wq i8 [4096][4096] (O-major, K contig)
    const int* __restrict__ gate,        // [4096][4]
    const float* __restrict__ scales,    // [4096]
    const int* __restrict__ rowlist,     // [4][4096] active row ids
    const int* __restrict__ zrowlist,    // [4][4096] gated-off row ids
    const int* __restrict__ counts,      // [4]
    float* __restrict__ out)             // [4096][4096] fp32
{
    const int tile = blockIdx.x >> 3;         // 8 n-blocks per gate tile
    const int cnt  = counts[tile];
    const int m0   = blockIdx.y * BM;         // position in compacted domain
    const int n0   = blockIdx.x * BN;
    const int nb   = (cnt + BM - 1) >> 7;     // # active by-blocks
    const int tid  = threadIdx.x;

    if (m0 >= cnt) {                          // ---- dead block: zero-fill slice ----
        const int zcnt  = M_DIM - cnt;
        const int ndead = 32 - nb;            // >0 (this block is dead)
        const int d     = blockIdx.y - nb;
        const int* zrl  = zrowlist + tile * M_DIM;
        const int r0 = (int)((long long)d * zcnt / ndead);
        const int r1 = (int)((long long)(d + 1) * zcnt / ndead);
        f32x4 z = {0.f, 0.f, 0.f, 0.f};
        for (int r = r0 + (tid >> 5); r < r1; r += 8) {   // 8 rows / pass
            int zrow = zrl[r];
            __builtin_nontemporal_store(
                z, (f32x4*)(out + (size_t)zrow * N_DIM + n0) + (tid & 31));
        }
        return;
    }

    __shared__ __align__(16) int8_t As[BM * BKB];   // 16 KB
    __shared__ __align__(16) int8_t Bs[BN * BKB];   // 16 KB

    const int lane = tid & 63;
    const int wave = tid >> 6;       // 0..3
    const int wm   = wave >> 1;      // 0..1
    const int wn   = wave & 1;       // 0..1
    const int quad = lane >> 4;      // 0..3
    const int ln16 = lane & 15;

    const int* rl = rowlist + tile * M_DIM;

    // ---- staging: 4 issues each for A and B per K-tile (1 KB per issue) ----
    const int srow   = lane >> 3;              // 0..7
    const int gchunk = (lane & 7) ^ srow;      // XOR swizzle in GLOBAL address
    const int8_t* a_src[4];
    const int8_t* b_src[4];
    int8_t* a_dst[4];
    int8_t* b_dst[4];
#pragma unroll
    for (int j = 0; j < 4; ++j) {
        int cidx = j * 4 + wave;
        int ra = m0 + cidx * 8 + srow;
        if (ra >= cnt) ra = cnt - 1;           // clamp surplus rows
        int grow = rl[ra];
        a_src[j] = A + (size_t)grow * K_DIM + gchunk * 16;
        b_src[j] = B + (size_t)(n0 + cidx * 8 + srow) * K_DIM + gchunk * 16;
        a_dst[j] = As + cidx * 1024;   // 8 rows x 128 B; HW adds lane*16B
        b_dst[j] = Bs + cidx * 1024;
    }

    // ---- fragment read addresses: lane reads 16 i8 at row, k = quad*16 + kk*64 ----
    const int8_t* a_rd[4][2];
    const int8_t* b_rd[4][2];
#pragma unroll
    for (int i = 0; i < 4; ++i) {
        int arow = wm * 64 + i * 16 + ln16;
        int brow = wn * 64 + i * 16 + ln16;
#pragma unroll
        for (int kk = 0; kk < 2; ++kk) {
            int ch = quad + 4 * kk;
            a_rd[i][kk] = As + arow * 128 + ((ch ^ (arow & 7)) * 16);
            b_rd[i][kk] = Bs + brow * 128 + ((ch ^ (brow & 7)) * 16);
        }
    }

    int4v acc[4][4];
#pragma unroll
    for (int i = 0; i < 4; ++i)
#pragma unroll
        for (int j = 0; j < 4; ++j)
            acc[i][j] = (int4v){0, 0, 0, 0};

    for (int kt = 0; kt < K_DIM; kt += BKB) {   // 32 tiles
#pragma unroll
        for (int j = 0; j < 4; ++j) {
            gload_lds16(a_src[j], a_dst[j]);
            gload_lds16(b_src[j], b_dst[j]);
        }
#pragma unroll
        for (int j = 0; j < 4; ++j) { a_src[j] += BKB; b_src[j] += BKB; }
        __syncthreads();

#pragma unroll
        for (int kk = 0; kk < 2; ++kk) {
            int4v af[4], bf[4];
#pragma unroll
            for (int i = 0; i < 4; ++i) af[i] = *(const int4v*)a_rd[i][kk];
#pragma unroll
            for (int i = 0; i < 4; ++i) bf[i] = *(const int4v*)b_rd[i][kk];
#pragma unroll
            for (int i = 0; i < 4; ++i)
#pragma unroll
                for (int j = 0; j < 4; ++j)
                    acc[i][j] = __builtin_amdgcn_mfma_i32_16x16x64_i8(
                        af[i], bf[j], acc[i][j], 0, 0, 0);
        }
        __syncthreads();
    }

    // ---- epilogue: out[grow] = acc_i32 * dq * scales[n] * gate[grow][tile] ----
    // Non-temporal: output is write-once; don't evict B panels from L2.
    float sc[4];
#pragma unroll
    for (int j = 0; j < 4; ++j) sc[j] = scales[n0 + wn * 64 + j * 16 + ln16] * XDEQ;

#pragma unroll
    for (int i = 0; i < 4; ++i) {
        int lbase = wm * 64 + i * 16 + quad * 4;
#pragma unroll
        for (int r = 0; r < 4; ++r) {
            int lr = lbase + r;
            if (m0 + lr < cnt) {
                int grow = rl[m0 + lr];
                float g = (float)gate[grow * NT + tile];   // generality: gate may be >1
                float* orow = out + (size_t)grow * N_DIM + n0 + wn * 64 + ln16;
#pragma unroll
                for (int j = 0; j < 4; ++j)
                    __builtin_nontemporal_store((float)acc[i][j][r] * sc[j] * g,
                                                &orow[j * 16]);
            }
        }
    }

    // ---- generality tail: cnt > 3968 leaves no dead blocks but zcnt>0 ----
    if (nb == 32 && blockIdx.y == 31) {
        const int zcnt = M_DIM - cnt;
        const int* zrl = zrowlist + tile * M_DIM;
        f32x4 z = {0.f, 0.f, 0.f, 0.f};
        for (int r = (tid >> 5); r < zcnt; r += 8) {
            int zrow = zrl[r];
            __builtin_nontemporal_store(
                z, (f32x4*)(out + (size_t)zrow * N_DIM + n0) + (tid & 31));
        }
    }
}

extern "C" void kernel_launch(void* const* d_in, const int* in_sizes, int n_in,
                              void* d_out, int out_size, void* d_ws, size_t ws_size,
                              hipStream_t stream) {
    const float* x      = (const float*)d_in[0];   // [4096][4096]
    const int*   gate   = (const int*)d_in[1];     // [4096][4]
    const float* weight = (const float*)d_in[2];   // [4096][4096]
    const float* scales = (const float*)d_in[3];   // [4096]
    float* out = (float*)d_out;

    int8_t* xq = (int8_t*)d_ws;                           // 16 MB i8 x
    int8_t* wq = xq + (size_t)M_DIM * K_DIM;              // 16 MB i8 W
    int* rowlist  = (int*)(wq + (size_t)N_DIM * K_DIM);   // 64 KB: 4 x 4096 row ids
    int* zrowlist = rowlist + NT * M_DIM;                 // 64 KB: complement
    int* counts   = zrowlist + NT * M_DIM;                // 16 B

    const int n8each = M_DIM * K_DIM / 8;                 // 2M threads per array
    cvt_i8_kernel<<<NCVB + NT, 256, 0, stream>>>(x, weight, xq, wq, gate,
                                                 rowlist, zrowlist, counts, n8each);

    dim3 grid(N_DIM / BN, M_DIM / BM);                    // 32 x 32 = 1024 blocks
    trix_gemm<<<grid, 256, 0, stream>>>(xq, wq, gate, scales,
                                        rowlist, zrowlist, counts, out);
}